// Round 6
// baseline (190.677 us; speedup 1.0000x reference)
//
#include <hip/hip_runtime.h>
#include <stdint.h>

#define GMAX 128
#define TK 128            // FG_ROIS_PER_IMAGE = BG_ROIS_PER_IMAGE = 128
#define NBINS 4096
#define CAND_MAX 4096
#define NUM_CLASSES 21
#define CBLOCK 1024

// ---------------------------------------------------------------------------
// JAX threefry2x32 block cipher (key = [hi32(seed), lo32(seed)] = [0, 42])
// ---------------------------------------------------------------------------
__device__ __forceinline__ void threefry2x32(uint32_t k0, uint32_t k1,
                                             uint32_t& x0, uint32_t& x1) {
  uint32_t ks0 = k0, ks1 = k1, ks2 = k0 ^ k1 ^ 0x1BD11BDAu;
  x0 += ks0; x1 += ks1;
#define TF_ROUND(r) { x0 += x1; x1 = (x1 << (r)) | (x1 >> (32 - (r))); x1 ^= x0; }
  TF_ROUND(13) TF_ROUND(15) TF_ROUND(26) TF_ROUND(6)
  x0 += ks1; x1 += ks2 + 1u;
  TF_ROUND(17) TF_ROUND(29) TF_ROUND(16) TF_ROUND(24)
  x0 += ks2; x1 += ks0 + 2u;
  TF_ROUND(13) TF_ROUND(15) TF_ROUND(26) TF_ROUND(6)
  x0 += ks0; x1 += ks1 + 3u;
  TF_ROUND(17) TF_ROUND(29) TF_ROUND(16) TF_ROUND(24)
  x0 += ks1; x1 += ks2 + 4u;
  TF_ROUND(13) TF_ROUND(15) TF_ROUND(26) TF_ROUND(6)
  x0 += ks2; x1 += ks0 + 5u;
#undef TF_ROUND
}

// ---------------------------------------------------------------------------
// Kernel 1: per-ROI max-IoU/argmax with 8x8 spatial cell culling.
// Cells are 128 px; covers use intervals [x1, x2+1] so that any pair with
// real iw>0 shares a cell (iw>0 <=> max(x1s) < min(x2s)+1). Culled pairs have
// fp-exact inter==0; argmax uses the order-independent rule
// (ov>best)||(ov==best&&g<bi), and best<=0 => bi=0 (all-zero row => argmax 0).
// Emits packed score [ubits23<<9 | gt(7b)<<2 | fg<<1 | bg] + fine histogram.
// ---------------------------------------------------------------------------
__global__ void __launch_bounds__(256)
score_kernel(const float* __restrict__ all_rois,   // [N,5]
             const float* __restrict__ gt_boxes,   // [G,4]
             uint32_t* __restrict__ score,         // [M]
             uint32_t* __restrict__ hist,          // [2*NBINS] fg|bg
             int N, int M, int G) {
  __shared__ float sgx1[GMAX], sgy1[GMAX], sgx2[GMAX], sgy2[GMAX], sga[GMAX];
  __shared__ int cnts[64];
  __shared__ uint16_t cell_start[65];
  __shared__ uint16_t entries[1216];   // worst case 128 gt x 9 cells = 1152
  const int t = threadIdx.x;

  if (t < G) {
    float x1 = gt_boxes[t * 4 + 0];
    float y1 = gt_boxes[t * 4 + 1];
    float x2 = gt_boxes[t * 4 + 2];
    float y2 = gt_boxes[t * 4 + 3];
    sgx1[t] = x1; sgy1[t] = y1; sgx2[t] = x2; sgy2[t] = y2;
    sga[t] = __fmul_rn(__fadd_rn(__fsub_rn(x2, x1), 1.0f),
                       __fadd_rn(__fsub_rn(y2, y1), 1.0f));
  }
  if (t < 64) cnts[t] = 0;
  __syncthreads();

  int gcx0 = 0, gcx1 = 0, gcy0 = 0, gcy1 = 0;
  if (t < G) {
    gcx0 = min(max((int)sgx1[t] >> 7, 0), 7);
    gcx1 = min(max((int)(sgx2[t] + 1.0f) >> 7, 0), 7);
    gcy0 = min(max((int)sgy1[t] >> 7, 0), 7);
    gcy1 = min(max((int)(sgy2[t] + 1.0f) >> 7, 0), 7);
    for (int cy = gcy0; cy <= gcy1; ++cy)
      for (int cx = gcx0; cx <= gcx1; ++cx)
        atomicAdd(&cnts[cy * 8 + cx], 1);
  }
  __syncthreads();
  if (t == 0) {
    int acc = 0;
    for (int k = 0; k < 64; ++k) {
      cell_start[k] = (uint16_t)acc;
      int c = cnts[k];
      cnts[k] = acc;          // becomes scatter cursor
      acc += c;
    }
    cell_start[64] = (uint16_t)acc;
  }
  __syncthreads();
  if (t < G) {
    for (int cy = gcy0; cy <= gcy1; ++cy)
      for (int cx = gcx0; cx <= gcx1; ++cx) {
        int p = atomicAdd(&cnts[cy * 8 + cx], 1);
        entries[p] = (uint16_t)t;
      }
  }
  __syncthreads();

  const int i = blockIdx.x * 256 + t;
  if (i >= M) return;

  float bx1, by1, bx2, by2;
  if (i < N) {
    bx1 = all_rois[(size_t)i * 5 + 1];
    by1 = all_rois[(size_t)i * 5 + 2];
    bx2 = all_rois[(size_t)i * 5 + 3];
    by2 = all_rois[(size_t)i * 5 + 4];
  } else {
    int g = i - N;
    bx1 = sgx1[g]; by1 = sgy1[g]; bx2 = sgx2[g]; by2 = sgy2[g];
  }
  const float area = __fmul_rn(__fadd_rn(__fsub_rn(bx2, bx1), 1.0f),
                               __fadd_rn(__fsub_rn(by2, by1), 1.0f));
  const int bcx0 = min(max((int)bx1 >> 7, 0), 7);
  const int bcx1 = min(max((int)(bx2 + 1.0f) >> 7, 0), 7);
  const int bcy0 = min(max((int)by1 >> 7, 0), 7);
  const int bcy1 = min(max((int)(by2 + 1.0f) >> 7, 0), 7);

  float best = -1.0f;
  int bi = 0;
  for (int cy = bcy0; cy <= bcy1; ++cy)
    for (int cx = bcx0; cx <= bcx1; ++cx) {
      const int c = cy * 8 + cx;
      const int e0 = cell_start[c], e1 = cell_start[c + 1];
      for (int e = e0; e < e1; ++e) {
        const int g = entries[e];
        float ix1 = fmaxf(bx1, sgx1[g]);
        float iy1 = fmaxf(by1, sgy1[g]);
        float ix2 = fminf(bx2, sgx2[g]);
        float iy2 = fminf(by2, sgy2[g]);
        float iw = fmaxf(__fadd_rn(__fsub_rn(ix2, ix1), 1.0f), 0.0f);
        float ih = fmaxf(__fadd_rn(__fsub_rn(iy2, iy1), 1.0f), 0.0f);
        float inter = __fmul_rn(iw, ih);
        float uni = __fsub_rn(__fadd_rn(area, sga[g]), inter);
        float ov = __fdiv_rn(inter, uni);           // IEEE, matches XLA
        if (ov > best || (ov == best && g < bi)) { best = ov; bi = g; }
      }
    }
  if (best <= 0.0f) bi = 0;           // max==0 => first index overall is 0
  const float maxov = (best < 0.0f) ? 0.0f : best;

  uint32_t cx0 = 0u, cx1 = (uint32_t)i;             // partitionable threefry
  threefry2x32(0u, 42u, cx0, cx1);
  uint32_t ubits = (cx0 ^ cx1) >> 9;

  uint32_t fg = (maxov >= 0.5f) ? 1u : 0u;
  uint32_t bg = (!fg && maxov >= 0.1f) ? 1u : 0u;
  score[i] = (ubits << 9) | ((uint32_t)bi << 2) | (fg << 1) | bg;
  if (fg)      atomicAdd(&hist[ubits >> 11], 1u);
  else if (bg) atomicAdd(&hist[NBINS + (ubits >> 11)], 1u);
}

// ---------------------------------------------------------------------------
// Kernel 2: compact + (last block) sort/finalize.
//  - wave 0 computes exact per-mask threshold bin from the fine histogram:
//    lane l sums fine bins [64l,64l+64) packed fg|bg in u64, wave suffix-scan,
//    ballot for the boundary lane, then one lane-parallel fine pass. Identical
//    result to the r5 serial walk: Bth = max b with count(bin>=b) >= TK.
//  - all threads filter one element each, appending candidates via atomics.
//  - LAST finishing block (release fence + done-counter; no spinning) sorts
//    candidates (key ((ubits+1)<<32)|~i == XLA stable top_k with
//    where(mask,u,-1.0) padding) and writes rois/labels/targets.
// ---------------------------------------------------------------------------
__global__ void __launch_bounds__(CBLOCK)
compact_final_kernel(const float* __restrict__ all_rois,
                     const float* __restrict__ gt_boxes,
                     const int* __restrict__ gt_labels,
                     const uint32_t* __restrict__ score,
                     const uint32_t* __restrict__ hist,
                     int* __restrict__ meta,      // [0]=cnt_fg [1]=cnt_bg [2]=done
                     uint64_t* __restrict__ cand_g,
                     float* __restrict__ out, int N, int M) {
  __shared__ int s_bth[2];
  __shared__ int s_last;
  __shared__ uint64_t cand[CAND_MAX];
  __shared__ int keep[2 * TK];
  __shared__ int fgvalid[TK];
  __shared__ float s_tx[2 * TK], s_ty[2 * TK], s_tw[2 * TK], s_th[2 * TK];
  __shared__ int s_label[2 * TK];
  const int t = threadIdx.x;

  // --- exact per-mask threshold (wave 0 only) ---
  if (t < 64) {
    const int base = t << 6;
    uint64_t csum = 0;
    for (int k = 0; k < 64; ++k)
      csum += ((uint64_t)hist[base + k] << 32) | (uint64_t)hist[NBINS + base + k];
    uint64_t S = csum;
#pragma unroll
    for (int d = 1; d < 64; d <<= 1) {
      uint64_t up = __shfl_down((unsigned long long)S, d, 64);
      if (t + d < 64) S += up;
    }
    for (int m = 0; m < 2; ++m) {
      uint32_t v = (m == 0) ? (uint32_t)(S >> 32) : (uint32_t)S;
      uint64_t bm = __ballot(v >= (uint32_t)TK);
      int B = -1;
      if (bm != 0ull) {
        int jl = 63 - __builtin_clzll(bm);
        uint32_t basecnt = 0;
        if (jl < 63) {
          uint64_t Sn = __shfl((unsigned long long)S, jl + 1, 64);
          basecnt = (m == 0) ? (uint32_t)(Sn >> 32) : (uint32_t)Sn;
        }
        uint32_t FS = hist[m * NBINS + (jl << 6) + t];
#pragma unroll
        for (int d = 1; d < 64; d <<= 1) {
          uint32_t up = __shfl_down(FS, d, 64);
          if (t + d < 64) FS += up;
        }
        FS += basecnt;
        uint64_t bm2 = __ballot(FS >= (uint32_t)TK);
        B = (jl << 6) + (63 - __builtin_clzll(bm2));
      }
      if (t == 0) s_bth[m] = B;
    }
  }
  __syncthreads();

  // --- filter (1 element / thread) ---
  const int i = blockIdx.x * CBLOCK + t;
  if (i < M) {
    uint32_t s = score[i];
    uint32_t mb = s & 3u;
    if (mb) {
      int m = (mb & 2u) ? 0 : 1;
      int B = s_bth[m];
      if (!(B >= 0 && (int)(s >> 20) < B)) {
        int p = atomicAdd(&meta[m], 1);
        if (p < CAND_MAX)
          cand_g[(size_t)m * CAND_MAX + p] =
              (((uint64_t)((s >> 9) + 1u)) << 32) | (uint64_t)(~(uint32_t)i);
      }
    }
  }

  // --- last-block handoff (no spin) ---
  __syncthreads();
  __threadfence();
  if (t == 0) {
    int old = __hip_atomic_fetch_add(&meta[2], 1, __ATOMIC_ACQ_REL,
                                     __HIP_MEMORY_SCOPE_AGENT);
    s_last = (old == (int)gridDim.x - 1) ? 1 : 0;
  }
  __syncthreads();
  if (!s_last) return;
  __threadfence();

  // --- epilogue: sort + finalize (verified r5 logic) ---
  for (int m = 0; m < 2; ++m) {
    int cnt = meta[m]; if (cnt > CAND_MAX) cnt = CAND_MAX;
    int P = TK;
    while (P < cnt) P <<= 1;
    for (int p = t; p < P; p += CBLOCK)
      cand[p] = (p < cnt) ? cand_g[(size_t)m * CAND_MAX + p] : 0ull;
    __syncthreads();
    for (int k = 2; k <= P; k <<= 1) {
      for (int j = k >> 1; j > 0; j >>= 1) {
        for (int idx = t; idx < P; idx += CBLOCK) {
          int l = idx ^ j;
          if (l > idx) {
            uint64_t a = cand[idx], b = cand[l];
            bool swp = ((idx & k) == 0) ? (a < b) : (a > b);
            if (swp) { cand[idx] = b; cand[l] = a; }
          }
        }
        __syncthreads();
      }
    }
    if (cnt < TK && t == 0) {       // mask had <TK members: pad with lowest-
      int fill = cnt;               // index non-masked (JAX -1.0 tie semantics)
      uint32_t mask_bit = (m == 0) ? 2u : 1u;
      for (int ii = 0; ii < M && fill < TK; ++ii)
        if (!(score[ii] & mask_bit)) cand[fill++] = (uint64_t)(~(uint32_t)ii);
    }
    __syncthreads();
    if (t < TK) {
      uint64_t c = cand[t];
      keep[m * TK + t] = (int)(~(uint32_t)(c & 0xFFFFFFFFull));
      if (m == 0) fgvalid[t] = ((c >> 32) != 0ull) ? 1 : 0;
    }
    __syncthreads();
  }

  const int R = 2 * TK;
  float* rois_out   = out;
  float* labels_out = out + (size_t)R * 5;
  float* bt_out     = out + (size_t)R * 5 + R;

  if (t < R) {
    const int ki = keep[t];
    float rimg, rx1, ry1, rx2, ry2;
    if (ki < N) {
      rimg = all_rois[(size_t)ki * 5 + 0];
      rx1  = all_rois[(size_t)ki * 5 + 1];
      ry1  = all_rois[(size_t)ki * 5 + 2];
      rx2  = all_rois[(size_t)ki * 5 + 3];
      ry2  = all_rois[(size_t)ki * 5 + 4];
    } else {
      int g = ki - N;
      rimg = 0.0f;
      rx1 = gt_boxes[g * 4 + 0]; ry1 = gt_boxes[g * 4 + 1];
      rx2 = gt_boxes[g * 4 + 2]; ry2 = gt_boxes[g * 4 + 3];
    }
    rois_out[t * 5 + 0] = rimg;
    rois_out[t * 5 + 1] = rx1;
    rois_out[t * 5 + 2] = ry1;
    rois_out[t * 5 + 3] = rx2;
    rois_out[t * 5 + 4] = ry2;

    const int ga = (int)((score[ki] >> 2) & 127u);
    int label = (t < TK && fgvalid[t]) ? gt_labels[ga] : 0;
    labels_out[t] = (float)label;
    s_label[t] = label;

    float gx1 = gt_boxes[ga * 4 + 0], gy1 = gt_boxes[ga * 4 + 1];
    float gx2 = gt_boxes[ga * 4 + 2], gy2 = gt_boxes[ga * 4 + 3];
    float ew = rx2 - rx1 + 1.0f, eh = ry2 - ry1 + 1.0f;
    float ecx = rx1 + 0.5f * ew, ecy = ry1 + 0.5f * eh;
    float gw = gx2 - gx1 + 1.0f, gh = gy2 - gy1 + 1.0f;
    float gcx = gx1 + 0.5f * gw, gcy = gy1 + 0.5f * gh;
    s_tx[t] = (gcx - ecx) / ew;
    s_ty[t] = (gcy - ecy) / eh;
    s_tw[t] = logf(gw / ew);
    s_th[t] = logf(gh / eh);
  }
  __syncthreads();

  const int TOT = R * 4 * NUM_CLASSES;
  for (int idx = t; idx < TOT; idx += CBLOCK) {
    int r = idx / (4 * NUM_CLASSES);
    int c = idx - r * (4 * NUM_CLASSES);
    int lab = s_label[r];
    float v = 0.0f;
    if (lab > 0 && (c >> 2) == lab) {
      int cc = c & 3;
      v = (cc == 0) ? s_tx[r] : (cc == 1) ? s_ty[r] : (cc == 2) ? s_tw[r] : s_th[r];
    }
    bt_out[idx] = v;
  }
}

// ---------------------------------------------------------------------------
extern "C" void kernel_launch(void* const* d_in, const int* in_sizes, int n_in,
                              void* d_out, int out_size, void* d_ws, size_t ws_size,
                              hipStream_t stream) {
  const float* all_rois = (const float*)d_in[0];
  const float* gt_boxes = (const float*)d_in[1];
  const int*   gt_labels = (const int*)d_in[2];
  const int N = in_sizes[0] / 5;
  const int G = in_sizes[2];
  const int M = N + G;

  // workspace: [meta 256B][hist 32KB][score M*4][cand 64KB]
  char* ws = (char*)d_ws;
  int* meta = (int*)ws;                       // [0]=cnt_fg [1]=cnt_bg [2]=done
  uint32_t* hist = (uint32_t*)(ws + 256);
  size_t off = 256 + (size_t)2 * NBINS * 4;
  uint32_t* score = (uint32_t*)(ws + off);
  off += (((size_t)M * 4) + 255) & ~(size_t)255;
  uint64_t* cand = (uint64_t*)(ws + off);
  float* out = (float*)d_out;

  hipMemsetAsync(ws, 0, 256 + (size_t)2 * NBINS * 4, stream);
  score_kernel<<<(M + 255) / 256, 256, 0, stream>>>(all_rois, gt_boxes, score,
                                                    hist, N, M, G);
  const int cblocks = (M + CBLOCK - 1) / CBLOCK;
  compact_final_kernel<<<cblocks, CBLOCK, 0, stream>>>(all_rois, gt_boxes,
                                                       gt_labels, score, hist,
                                                       meta, cand, out, N, M);
}

// Round 7
// 131.845 us; speedup vs baseline: 1.4462x; 1.4462x over previous
//
#include <hip/hip_runtime.h>
#include <stdint.h>

#define GMAX 128
#define TK 128            // FG_ROIS_PER_IMAGE = BG_ROIS_PER_IMAGE = 128
#define NBINS 4096
#define CAND_MAX 4096
#define NUM_CLASSES 21
#define CBLOCK 1024

// ---------------------------------------------------------------------------
// JAX threefry2x32 block cipher (key = [hi32(seed), lo32(seed)] = [0, 42])
// ---------------------------------------------------------------------------
__device__ __forceinline__ void threefry2x32(uint32_t k0, uint32_t k1,
                                             uint32_t& x0, uint32_t& x1) {
  uint32_t ks0 = k0, ks1 = k1, ks2 = k0 ^ k1 ^ 0x1BD11BDAu;
  x0 += ks0; x1 += ks1;
#define TF_ROUND(r) { x0 += x1; x1 = (x1 << (r)) | (x1 >> (32 - (r))); x1 ^= x0; }
  TF_ROUND(13) TF_ROUND(15) TF_ROUND(26) TF_ROUND(6)
  x0 += ks1; x1 += ks2 + 1u;
  TF_ROUND(17) TF_ROUND(29) TF_ROUND(16) TF_ROUND(24)
  x0 += ks2; x1 += ks0 + 2u;
  TF_ROUND(13) TF_ROUND(15) TF_ROUND(26) TF_ROUND(6)
  x0 += ks0; x1 += ks1 + 3u;
  TF_ROUND(17) TF_ROUND(29) TF_ROUND(16) TF_ROUND(24)
  x0 += ks1; x1 += ks2 + 4u;
  TF_ROUND(13) TF_ROUND(15) TF_ROUND(26) TF_ROUND(6)
  x0 += ks2; x1 += ks0 + 5u;
#undef TF_ROUND
}

// ---------------------------------------------------------------------------
// Kernel 1 (verified r6): per-ROI max-IoU/argmax with 8x8 spatial cell
// culling (128-px cells; covers [x1,x2+1] so any pair with real iw>0 shares a
// cell; culled pairs have fp-exact inter==0). Order-independent argmax rule
// (ov>best)||(ov==best&&g<bi); best<=0 => bi=0. Emits packed score
// [ubits23<<9 | gt(7b)<<2 | fg<<1 | bg] + fine histogram (4096 bins/mask).
// ---------------------------------------------------------------------------
__global__ void __launch_bounds__(256)
score_kernel(const float* __restrict__ all_rois,   // [N,5]
             const float* __restrict__ gt_boxes,   // [G,4]
             uint32_t* __restrict__ score,         // [M]
             uint32_t* __restrict__ hist,          // [2*NBINS] fg|bg
             int N, int M, int G) {
  __shared__ float sgx1[GMAX], sgy1[GMAX], sgx2[GMAX], sgy2[GMAX], sga[GMAX];
  __shared__ int cnts[64];
  __shared__ uint16_t cell_start[65];
  __shared__ uint16_t entries[1216];   // worst case 128 gt x 9 cells = 1152
  const int t = threadIdx.x;

  if (t < G) {
    float x1 = gt_boxes[t * 4 + 0];
    float y1 = gt_boxes[t * 4 + 1];
    float x2 = gt_boxes[t * 4 + 2];
    float y2 = gt_boxes[t * 4 + 3];
    sgx1[t] = x1; sgy1[t] = y1; sgx2[t] = x2; sgy2[t] = y2;
    sga[t] = __fmul_rn(__fadd_rn(__fsub_rn(x2, x1), 1.0f),
                       __fadd_rn(__fsub_rn(y2, y1), 1.0f));
  }
  if (t < 64) cnts[t] = 0;
  __syncthreads();

  int gcx0 = 0, gcx1 = 0, gcy0 = 0, gcy1 = 0;
  if (t < G) {
    gcx0 = min(max((int)sgx1[t] >> 7, 0), 7);
    gcx1 = min(max((int)(sgx2[t] + 1.0f) >> 7, 0), 7);
    gcy0 = min(max((int)sgy1[t] >> 7, 0), 7);
    gcy1 = min(max((int)(sgy2[t] + 1.0f) >> 7, 0), 7);
    for (int cy = gcy0; cy <= gcy1; ++cy)
      for (int cx = gcx0; cx <= gcx1; ++cx)
        atomicAdd(&cnts[cy * 8 + cx], 1);
  }
  __syncthreads();
  if (t == 0) {
    int acc = 0;
    for (int k = 0; k < 64; ++k) {
      cell_start[k] = (uint16_t)acc;
      int c = cnts[k];
      cnts[k] = acc;          // becomes scatter cursor
      acc += c;
    }
    cell_start[64] = (uint16_t)acc;
  }
  __syncthreads();
  if (t < G) {
    for (int cy = gcy0; cy <= gcy1; ++cy)
      for (int cx = gcx0; cx <= gcx1; ++cx) {
        int p = atomicAdd(&cnts[cy * 8 + cx], 1);
        entries[p] = (uint16_t)t;
      }
  }
  __syncthreads();

  const int i = blockIdx.x * 256 + t;
  if (i >= M) return;

  float bx1, by1, bx2, by2;
  if (i < N) {
    bx1 = all_rois[(size_t)i * 5 + 1];
    by1 = all_rois[(size_t)i * 5 + 2];
    bx2 = all_rois[(size_t)i * 5 + 3];
    by2 = all_rois[(size_t)i * 5 + 4];
  } else {
    int g = i - N;
    bx1 = sgx1[g]; by1 = sgy1[g]; bx2 = sgx2[g]; by2 = sgy2[g];
  }
  const float area = __fmul_rn(__fadd_rn(__fsub_rn(bx2, bx1), 1.0f),
                               __fadd_rn(__fsub_rn(by2, by1), 1.0f));
  const int bcx0 = min(max((int)bx1 >> 7, 0), 7);
  const int bcx1 = min(max((int)(bx2 + 1.0f) >> 7, 0), 7);
  const int bcy0 = min(max((int)by1 >> 7, 0), 7);
  const int bcy1 = min(max((int)(by2 + 1.0f) >> 7, 0), 7);

  float best = -1.0f;
  int bi = 0;
  for (int cy = bcy0; cy <= bcy1; ++cy)
    for (int cx = bcx0; cx <= bcx1; ++cx) {
      const int c = cy * 8 + cx;
      const int e0 = cell_start[c], e1 = cell_start[c + 1];
      for (int e = e0; e < e1; ++e) {
        const int g = entries[e];
        float ix1 = fmaxf(bx1, sgx1[g]);
        float iy1 = fmaxf(by1, sgy1[g]);
        float ix2 = fminf(bx2, sgx2[g]);
        float iy2 = fminf(by2, sgy2[g]);
        float iw = fmaxf(__fadd_rn(__fsub_rn(ix2, ix1), 1.0f), 0.0f);
        float ih = fmaxf(__fadd_rn(__fsub_rn(iy2, iy1), 1.0f), 0.0f);
        float inter = __fmul_rn(iw, ih);
        float uni = __fsub_rn(__fadd_rn(area, sga[g]), inter);
        float ov = __fdiv_rn(inter, uni);           // IEEE, matches XLA
        if (ov > best || (ov == best && g < bi)) { best = ov; bi = g; }
      }
    }
  if (best <= 0.0f) bi = 0;           // max==0 => first index overall is 0
  const float maxov = (best < 0.0f) ? 0.0f : best;

  uint32_t cx0 = 0u, cx1 = (uint32_t)i;             // partitionable threefry
  threefry2x32(0u, 42u, cx0, cx1);
  uint32_t ubits = (cx0 ^ cx1) >> 9;

  uint32_t fg = (maxov >= 0.5f) ? 1u : 0u;
  uint32_t bg = (!fg && maxov >= 0.1f) ? 1u : 0u;
  score[i] = (ubits << 9) | ((uint32_t)bi << 2) | (fg << 1) | bg;
  if (fg)      atomicAdd(&hist[ubits >> 11], 1u);
  else if (bg) atomicAdd(&hist[NBINS + (ubits >> 11)], 1u);
}

// ---------------------------------------------------------------------------
// Kernel 2: compact + (last block) sort/finalize.
// Handoff discipline (r6 lesson): NO per-wave/per-thread __threadfence() —
// an agent-scope release fence is an L2 writeback sweep on multi-XCD gfx950;
// 3920 of them cost ~98us. Instead: __syncthreads() drains each wave's
// stores (compiler emits s_waitcnt vmcnt(0) before s_barrier), then ONE
// thread per block issues the ACQ_REL done-counter RMW (one wbl2+inv per
// block). The last block's acquire invalidates stale L1/L2 before reading
// the other blocks' candidate stores.
// ---------------------------------------------------------------------------
__global__ void __launch_bounds__(CBLOCK)
compact_final_kernel(const float* __restrict__ all_rois,
                     const float* __restrict__ gt_boxes,
                     const int* __restrict__ gt_labels,
                     const uint32_t* __restrict__ score,
                     const uint32_t* __restrict__ hist,
                     int* __restrict__ meta,      // [0]=cnt_fg [1]=cnt_bg [2]=done
                     uint64_t* __restrict__ cand_g,
                     float* __restrict__ out, int N, int M) {
  __shared__ int s_bth[2];
  __shared__ int s_last;
  __shared__ uint64_t cand[CAND_MAX];
  __shared__ int keep[2 * TK];
  __shared__ int fgvalid[TK];
  __shared__ float s_tx[2 * TK], s_ty[2 * TK], s_tw[2 * TK], s_th[2 * TK];
  __shared__ int s_label[2 * TK];
  const int t = threadIdx.x;

  // --- exact per-mask threshold (wave 0 only; verified r6) ---
  if (t < 64) {
    const int base = t << 6;
    uint64_t csum = 0;
    for (int k = 0; k < 64; ++k)
      csum += ((uint64_t)hist[base + k] << 32) | (uint64_t)hist[NBINS + base + k];
    uint64_t S = csum;
#pragma unroll
    for (int d = 1; d < 64; d <<= 1) {
      uint64_t up = __shfl_down((unsigned long long)S, d, 64);
      if (t + d < 64) S += up;
    }
    for (int m = 0; m < 2; ++m) {
      uint32_t v = (m == 0) ? (uint32_t)(S >> 32) : (uint32_t)S;
      uint64_t bm = __ballot(v >= (uint32_t)TK);
      int B = -1;
      if (bm != 0ull) {
        int jl = 63 - __builtin_clzll(bm);
        uint32_t basecnt = 0;
        if (jl < 63) {
          uint64_t Sn = __shfl((unsigned long long)S, jl + 1, 64);
          basecnt = (m == 0) ? (uint32_t)(Sn >> 32) : (uint32_t)Sn;
        }
        uint32_t FS = hist[m * NBINS + (jl << 6) + t];
#pragma unroll
        for (int d = 1; d < 64; d <<= 1) {
          uint32_t up = __shfl_down(FS, d, 64);
          if (t + d < 64) FS += up;
        }
        FS += basecnt;
        uint64_t bm2 = __ballot(FS >= (uint32_t)TK);
        B = (jl << 6) + (63 - __builtin_clzll(bm2));
      }
      if (t == 0) s_bth[m] = B;
    }
  }
  __syncthreads();

  // --- filter (1 element / thread) ---
  const int i = blockIdx.x * CBLOCK + t;
  if (i < M) {
    uint32_t s = score[i];
    uint32_t mb = s & 3u;
    if (mb) {
      int m = (mb & 2u) ? 0 : 1;
      int B = s_bth[m];
      if (!(B >= 0 && (int)(s >> 20) < B)) {
        int p = atomicAdd(&meta[m], 1);
        if (p < CAND_MAX)
          cand_g[(size_t)m * CAND_MAX + p] =
              (((uint64_t)((s >> 9) + 1u)) << 32) | (uint64_t)(~(uint32_t)i);
      }
    }
  }

  // --- last-block handoff: one ACQ_REL RMW per block, thread 0 only ---
  __syncthreads();     // drains vmcnt(0) per wave: block stores are in L2
  if (t == 0) {
    int old = __hip_atomic_fetch_add(&meta[2], 1, __ATOMIC_ACQ_REL,
                                     __HIP_MEMORY_SCOPE_AGENT);
    s_last = (old == (int)gridDim.x - 1) ? 1 : 0;
  }
  __syncthreads();
  if (!s_last) return;

  // --- epilogue: sort + finalize (verified r5/r6 logic) ---
  for (int m = 0; m < 2; ++m) {
    int cnt = meta[m]; if (cnt > CAND_MAX) cnt = CAND_MAX;
    int P = TK;
    while (P < cnt) P <<= 1;
    for (int p = t; p < P; p += CBLOCK)
      cand[p] = (p < cnt) ? cand_g[(size_t)m * CAND_MAX + p] : 0ull;
    __syncthreads();
    for (int k = 2; k <= P; k <<= 1) {
      for (int j = k >> 1; j > 0; j >>= 1) {
        for (int idx = t; idx < P; idx += CBLOCK) {
          int l = idx ^ j;
          if (l > idx) {
            uint64_t a = cand[idx], b = cand[l];
            bool swp = ((idx & k) == 0) ? (a < b) : (a > b);
            if (swp) { cand[idx] = b; cand[l] = a; }
          }
        }
        __syncthreads();
      }
    }
    if (cnt < TK && t == 0) {       // mask had <TK members: pad with lowest-
      int fill = cnt;               // index non-masked (JAX -1.0 tie semantics)
      uint32_t mask_bit = (m == 0) ? 2u : 1u;
      for (int ii = 0; ii < M && fill < TK; ++ii)
        if (!(score[ii] & mask_bit)) cand[fill++] = (uint64_t)(~(uint32_t)ii);
    }
    __syncthreads();
    if (t < TK) {
      uint64_t c = cand[t];
      keep[m * TK + t] = (int)(~(uint32_t)(c & 0xFFFFFFFFull));
      if (m == 0) fgvalid[t] = ((c >> 32) != 0ull) ? 1 : 0;
    }
    __syncthreads();
  }

  const int R = 2 * TK;
  float* rois_out   = out;
  float* labels_out = out + (size_t)R * 5;
  float* bt_out     = out + (size_t)R * 5 + R;

  if (t < R) {
    const int ki = keep[t];
    float rimg, rx1, ry1, rx2, ry2;
    if (ki < N) {
      rimg = all_rois[(size_t)ki * 5 + 0];
      rx1  = all_rois[(size_t)ki * 5 + 1];
      ry1  = all_rois[(size_t)ki * 5 + 2];
      rx2  = all_rois[(size_t)ki * 5 + 3];
      ry2  = all_rois[(size_t)ki * 5 + 4];
    } else {
      int g = ki - N;
      rimg = 0.0f;
      rx1 = gt_boxes[g * 4 + 0]; ry1 = gt_boxes[g * 4 + 1];
      rx2 = gt_boxes[g * 4 + 2]; ry2 = gt_boxes[g * 4 + 3];
    }
    rois_out[t * 5 + 0] = rimg;
    rois_out[t * 5 + 1] = rx1;
    rois_out[t * 5 + 2] = ry1;
    rois_out[t * 5 + 3] = rx2;
    rois_out[t * 5 + 4] = ry2;

    const int ga = (int)((score[ki] >> 2) & 127u);
    int label = (t < TK && fgvalid[t]) ? gt_labels[ga] : 0;
    labels_out[t] = (float)label;
    s_label[t] = label;

    float gx1 = gt_boxes[ga * 4 + 0], gy1 = gt_boxes[ga * 4 + 1];
    float gx2 = gt_boxes[ga * 4 + 2], gy2 = gt_boxes[ga * 4 + 3];
    float ew = rx2 - rx1 + 1.0f, eh = ry2 - ry1 + 1.0f;
    float ecx = rx1 + 0.5f * ew, ecy = ry1 + 0.5f * eh;
    float gw = gx2 - gx1 + 1.0f, gh = gy2 - gy1 + 1.0f;
    float gcx = gx1 + 0.5f * gw, gcy = gy1 + 0.5f * gh;
    s_tx[t] = (gcx - ecx) / ew;
    s_ty[t] = (gcy - ecy) / eh;
    s_tw[t] = logf(gw / ew);
    s_th[t] = logf(gh / eh);
  }
  __syncthreads();

  const int TOT = R * 4 * NUM_CLASSES;
  for (int idx = t; idx < TOT; idx += CBLOCK) {
    int r = idx / (4 * NUM_CLASSES);
    int c = idx - r * (4 * NUM_CLASSES);
    int lab = s_label[r];
    float v = 0.0f;
    if (lab > 0 && (c >> 2) == lab) {
      int cc = c & 3;
      v = (cc == 0) ? s_tx[r] : (cc == 1) ? s_ty[r] : (cc == 2) ? s_tw[r] : s_th[r];
    }
    bt_out[idx] = v;
  }
}

// ---------------------------------------------------------------------------
extern "C" void kernel_launch(void* const* d_in, const int* in_sizes, int n_in,
                              void* d_out, int out_size, void* d_ws, size_t ws_size,
                              hipStream_t stream) {
  const float* all_rois = (const float*)d_in[0];
  const float* gt_boxes = (const float*)d_in[1];
  const int*   gt_labels = (const int*)d_in[2];
  const int N = in_sizes[0] / 5;
  const int G = in_sizes[2];
  const int M = N + G;

  // workspace: [meta 256B][hist 32KB][score M*4][cand 64KB]
  char* ws = (char*)d_ws;
  int* meta = (int*)ws;                       // [0]=cnt_fg [1]=cnt_bg [2]=done
  uint32_t* hist = (uint32_t*)(ws + 256);
  size_t off = 256 + (size_t)2 * NBINS * 4;
  uint32_t* score = (uint32_t*)(ws + off);
  off += (((size_t)M * 4) + 255) & ~(size_t)255;
  uint64_t* cand = (uint64_t*)(ws + off);
  float* out = (float*)d_out;

  hipMemsetAsync(ws, 0, 256 + (size_t)2 * NBINS * 4, stream);
  score_kernel<<<(M + 255) / 256, 256, 0, stream>>>(all_rois, gt_boxes, score,
                                                    hist, N, M, G);
  const int cblocks = (M + CBLOCK - 1) / CBLOCK;
  compact_final_kernel<<<cblocks, CBLOCK, 0, stream>>>(all_rois, gt_boxes,
                                                       gt_labels, score, hist,
                                                       meta, cand, out, N, M);
}

// Round 8
// 119.921 us; speedup vs baseline: 1.5900x; 1.0994x over previous
//
#include <hip/hip_runtime.h>
#include <stdint.h>

#define GMAX 128
#define TK 128            // FG_ROIS_PER_IMAGE = BG_ROIS_PER_IMAGE = 128
#define NBINS 4096
#define CAND_MAX 4096
#define NUM_CLASSES 21
#define CBLOCK 1024

// ---------------------------------------------------------------------------
// JAX threefry2x32 block cipher (key = [hi32(seed), lo32(seed)] = [0, 42])
// ---------------------------------------------------------------------------
__device__ __forceinline__ void threefry2x32(uint32_t k0, uint32_t k1,
                                             uint32_t& x0, uint32_t& x1) {
  uint32_t ks0 = k0, ks1 = k1, ks2 = k0 ^ k1 ^ 0x1BD11BDAu;
  x0 += ks0; x1 += ks1;
#define TF_ROUND(r) { x0 += x1; x1 = (x1 << (r)) | (x1 >> (32 - (r))); x1 ^= x0; }
  TF_ROUND(13) TF_ROUND(15) TF_ROUND(26) TF_ROUND(6)
  x0 += ks1; x1 += ks2 + 1u;
  TF_ROUND(17) TF_ROUND(29) TF_ROUND(16) TF_ROUND(24)
  x0 += ks2; x1 += ks0 + 2u;
  TF_ROUND(13) TF_ROUND(15) TF_ROUND(26) TF_ROUND(6)
  x0 += ks0; x1 += ks1 + 3u;
  TF_ROUND(17) TF_ROUND(29) TF_ROUND(16) TF_ROUND(24)
  x0 += ks1; x1 += ks2 + 4u;
  TF_ROUND(13) TF_ROUND(15) TF_ROUND(26) TF_ROUND(6)
  x0 += ks2; x1 += ks0 + 5u;
#undef TF_ROUND
}

// ---------------------------------------------------------------------------
// Kernel 1 (r5-verified structure): per-ROI max-IoU over ALL G gts with
// wave-uniform LDS broadcast reads (conflict-free — r7 showed lane-divergent
// LDS gathers cost 2M conflict cycles and 4x the time). First-max argmax
// == jnp.argmax. Emits packed score [ubits23<<9 | gt(7b)<<2 | fg<<1 | bg]
// + fine histogram (4096 bins/mask) of threefry-uniform mantissa bits.
// ---------------------------------------------------------------------------
__global__ void __launch_bounds__(256)
score_kernel(const float* __restrict__ all_rois,   // [N,5]
             const float* __restrict__ gt_boxes,   // [G,4]
             uint32_t* __restrict__ score,         // [M]
             uint32_t* __restrict__ hist,          // [2*NBINS] fg|bg
             int N, int M, int G) {
  __shared__ float sgx1[GMAX], sgy1[GMAX], sgx2[GMAX], sgy2[GMAX], sga[GMAX];
  const int t = threadIdx.x;
  if (t < G) {
    float x1 = gt_boxes[t * 4 + 0];
    float y1 = gt_boxes[t * 4 + 1];
    float x2 = gt_boxes[t * 4 + 2];
    float y2 = gt_boxes[t * 4 + 3];
    sgx1[t] = x1; sgy1[t] = y1; sgx2[t] = x2; sgy2[t] = y2;
    sga[t] = __fmul_rn(__fadd_rn(__fsub_rn(x2, x1), 1.0f),
                       __fadd_rn(__fsub_rn(y2, y1), 1.0f));
  }
  __syncthreads();
  const int i = blockIdx.x * 256 + t;
  if (i >= M) return;

  float bx1, by1, bx2, by2;
  if (i < N) {
    bx1 = all_rois[(size_t)i * 5 + 1];
    by1 = all_rois[(size_t)i * 5 + 2];
    bx2 = all_rois[(size_t)i * 5 + 3];
    by2 = all_rois[(size_t)i * 5 + 4];
  } else {
    int g = i - N;
    bx1 = sgx1[g]; by1 = sgy1[g]; bx2 = sgx2[g]; by2 = sgy2[g];
  }
  const float area = __fmul_rn(__fadd_rn(__fsub_rn(bx2, bx1), 1.0f),
                               __fadd_rn(__fsub_rn(by2, by1), 1.0f));
  float best = -1.0f;
  int bi = 0;
  for (int g = 0; g < G; ++g) {      // wave-uniform g -> LDS broadcast reads
    float ix1 = fmaxf(bx1, sgx1[g]);
    float iy1 = fmaxf(by1, sgy1[g]);
    float ix2 = fminf(bx2, sgx2[g]);
    float iy2 = fminf(by2, sgy2[g]);
    float iw = fmaxf(__fadd_rn(__fsub_rn(ix2, ix1), 1.0f), 0.0f);
    float ih = fmaxf(__fadd_rn(__fsub_rn(iy2, iy1), 1.0f), 0.0f);
    float inter = __fmul_rn(iw, ih);
    float uni = __fsub_rn(__fadd_rn(area, sga[g]), inter);
    float ov = __fdiv_rn(inter, uni);               // IEEE-rounded, matches XLA
    if (ov > best) { best = ov; bi = g; }           // first-max == jnp.argmax
  }

  // partitionable threefry: counter (hi=0, lo=i), output = x0 ^ x1
  uint32_t cx0 = 0u, cx1 = (uint32_t)i;
  threefry2x32(0u, 42u, cx0, cx1);
  uint32_t ubits = (cx0 ^ cx1) >> 9;                // mantissa of u in [0,1)

  uint32_t fg = (best >= 0.5f) ? 1u : 0u;
  uint32_t bg = (!fg && best >= 0.1f) ? 1u : 0u;
  score[i] = (ubits << 9) | ((uint32_t)bi << 2) | (fg << 1) | bg;
  if (fg)      atomicAdd(&hist[ubits >> 11], 1u);
  else if (bg) atomicAdd(&hist[NBINS + (ubits >> 11)], 1u);
}

// ---------------------------------------------------------------------------
// Kernel 2 (r7-verified): compact + (last block) sort/finalize.
// Handoff discipline (r6 lesson): NO per-wave/per-thread __threadfence() —
// an agent-scope release fence is an L2 writeback sweep on multi-XCD gfx950;
// thousands of them cost ~98us. Instead: __syncthreads() drains each wave's
// stores (compiler emits s_waitcnt vmcnt(0) before s_barrier), then ONE
// thread per block issues the ACQ_REL done-counter RMW (one wbl2+inv per
// block). The last block's acquire invalidates stale caches before reading
// the other blocks' candidate stores.
// ---------------------------------------------------------------------------
__global__ void __launch_bounds__(CBLOCK)
compact_final_kernel(const float* __restrict__ all_rois,
                     const float* __restrict__ gt_boxes,
                     const int* __restrict__ gt_labels,
                     const uint32_t* __restrict__ score,
                     const uint32_t* __restrict__ hist,
                     int* __restrict__ meta,      // [0]=cnt_fg [1]=cnt_bg [2]=done
                     uint64_t* __restrict__ cand_g,
                     float* __restrict__ out, int N, int M) {
  __shared__ int s_bth[2];
  __shared__ int s_last;
  __shared__ uint64_t cand[CAND_MAX];
  __shared__ int keep[2 * TK];
  __shared__ int fgvalid[TK];
  __shared__ float s_tx[2 * TK], s_ty[2 * TK], s_tw[2 * TK], s_th[2 * TK];
  __shared__ int s_label[2 * TK];
  const int t = threadIdx.x;

  // --- exact per-mask threshold (wave 0 only; verified r6/r7) ---
  if (t < 64) {
    const int base = t << 6;
    uint64_t csum = 0;
    for (int k = 0; k < 64; ++k)
      csum += ((uint64_t)hist[base + k] << 32) | (uint64_t)hist[NBINS + base + k];
    uint64_t S = csum;
#pragma unroll
    for (int d = 1; d < 64; d <<= 1) {
      uint64_t up = __shfl_down((unsigned long long)S, d, 64);
      if (t + d < 64) S += up;
    }
    for (int m = 0; m < 2; ++m) {
      uint32_t v = (m == 0) ? (uint32_t)(S >> 32) : (uint32_t)S;
      uint64_t bm = __ballot(v >= (uint32_t)TK);
      int B = -1;
      if (bm != 0ull) {
        int jl = 63 - __builtin_clzll(bm);
        uint32_t basecnt = 0;
        if (jl < 63) {
          uint64_t Sn = __shfl((unsigned long long)S, jl + 1, 64);
          basecnt = (m == 0) ? (uint32_t)(Sn >> 32) : (uint32_t)Sn;
        }
        uint32_t FS = hist[m * NBINS + (jl << 6) + t];
#pragma unroll
        for (int d = 1; d < 64; d <<= 1) {
          uint32_t up = __shfl_down(FS, d, 64);
          if (t + d < 64) FS += up;
        }
        FS += basecnt;
        uint64_t bm2 = __ballot(FS >= (uint32_t)TK);
        B = (jl << 6) + (63 - __builtin_clzll(bm2));
      }
      if (t == 0) s_bth[m] = B;
    }
  }
  __syncthreads();

  // --- filter (1 element / thread) ---
  const int i = blockIdx.x * CBLOCK + t;
  if (i < M) {
    uint32_t s = score[i];
    uint32_t mb = s & 3u;
    if (mb) {
      int m = (mb & 2u) ? 0 : 1;
      int B = s_bth[m];
      if (!(B >= 0 && (int)(s >> 20) < B)) {
        int p = atomicAdd(&meta[m], 1);
        if (p < CAND_MAX)
          cand_g[(size_t)m * CAND_MAX + p] =
              (((uint64_t)((s >> 9) + 1u)) << 32) | (uint64_t)(~(uint32_t)i);
      }
    }
  }

  // --- last-block handoff: one ACQ_REL RMW per block, thread 0 only ---
  __syncthreads();     // drains vmcnt(0) per wave: block stores are in L2
  if (t == 0) {
    int old = __hip_atomic_fetch_add(&meta[2], 1, __ATOMIC_ACQ_REL,
                                     __HIP_MEMORY_SCOPE_AGENT);
    s_last = (old == (int)gridDim.x - 1) ? 1 : 0;
  }
  __syncthreads();
  if (!s_last) return;

  // --- epilogue: sort + finalize (verified r5/r6/r7 logic) ---
  for (int m = 0; m < 2; ++m) {
    int cnt = meta[m]; if (cnt > CAND_MAX) cnt = CAND_MAX;
    int P = TK;
    while (P < cnt) P <<= 1;
    for (int p = t; p < P; p += CBLOCK)
      cand[p] = (p < cnt) ? cand_g[(size_t)m * CAND_MAX + p] : 0ull;
    __syncthreads();
    for (int k = 2; k <= P; k <<= 1) {
      for (int j = k >> 1; j > 0; j >>= 1) {
        for (int idx = t; idx < P; idx += CBLOCK) {
          int l = idx ^ j;
          if (l > idx) {
            uint64_t a = cand[idx], b = cand[l];
            bool swp = ((idx & k) == 0) ? (a < b) : (a > b);
            if (swp) { cand[idx] = b; cand[l] = a; }
          }
        }
        __syncthreads();
      }
    }
    if (cnt < TK && t == 0) {       // mask had <TK members: pad with lowest-
      int fill = cnt;               // index non-masked (JAX -1.0 tie semantics)
      uint32_t mask_bit = (m == 0) ? 2u : 1u;
      for (int ii = 0; ii < M && fill < TK; ++ii)
        if (!(score[ii] & mask_bit)) cand[fill++] = (uint64_t)(~(uint32_t)ii);
    }
    __syncthreads();
    if (t < TK) {
      uint64_t c = cand[t];
      keep[m * TK + t] = (int)(~(uint32_t)(c & 0xFFFFFFFFull));
      if (m == 0) fgvalid[t] = ((c >> 32) != 0ull) ? 1 : 0;
    }
    __syncthreads();
  }

  const int R = 2 * TK;
  float* rois_out   = out;
  float* labels_out = out + (size_t)R * 5;
  float* bt_out     = out + (size_t)R * 5 + R;

  if (t < R) {
    const int ki = keep[t];
    float rimg, rx1, ry1, rx2, ry2;
    if (ki < N) {
      rimg = all_rois[(size_t)ki * 5 + 0];
      rx1  = all_rois[(size_t)ki * 5 + 1];
      ry1  = all_rois[(size_t)ki * 5 + 2];
      rx2  = all_rois[(size_t)ki * 5 + 3];
      ry2  = all_rois[(size_t)ki * 5 + 4];
    } else {
      int g = ki - N;
      rimg = 0.0f;
      rx1 = gt_boxes[g * 4 + 0]; ry1 = gt_boxes[g * 4 + 1];
      rx2 = gt_boxes[g * 4 + 2]; ry2 = gt_boxes[g * 4 + 3];
    }
    rois_out[t * 5 + 0] = rimg;
    rois_out[t * 5 + 1] = rx1;
    rois_out[t * 5 + 2] = ry1;
    rois_out[t * 5 + 3] = rx2;
    rois_out[t * 5 + 4] = ry2;

    const int ga = (int)((score[ki] >> 2) & 127u);
    int label = (t < TK && fgvalid[t]) ? gt_labels[ga] : 0;
    labels_out[t] = (float)label;
    s_label[t] = label;

    float gx1 = gt_boxes[ga * 4 + 0], gy1 = gt_boxes[ga * 4 + 1];
    float gx2 = gt_boxes[ga * 4 + 2], gy2 = gt_boxes[ga * 4 + 3];
    float ew = rx2 - rx1 + 1.0f, eh = ry2 - ry1 + 1.0f;
    float ecx = rx1 + 0.5f * ew, ecy = ry1 + 0.5f * eh;
    float gw = gx2 - gx1 + 1.0f, gh = gy2 - gy1 + 1.0f;
    float gcx = gx1 + 0.5f * gw, gcy = gy1 + 0.5f * gh;
    s_tx[t] = (gcx - ecx) / ew;
    s_ty[t] = (gcy - ecy) / eh;
    s_tw[t] = logf(gw / ew);
    s_th[t] = logf(gh / eh);
  }
  __syncthreads();

  const int TOT = R * 4 * NUM_CLASSES;
  for (int idx = t; idx < TOT; idx += CBLOCK) {
    int r = idx / (4 * NUM_CLASSES);
    int c = idx - r * (4 * NUM_CLASSES);
    int lab = s_label[r];
    float v = 0.0f;
    if (lab > 0 && (c >> 2) == lab) {
      int cc = c & 3;
      v = (cc == 0) ? s_tx[r] : (cc == 1) ? s_ty[r] : (cc == 2) ? s_tw[r] : s_th[r];
    }
    bt_out[idx] = v;
  }
}

// ---------------------------------------------------------------------------
extern "C" void kernel_launch(void* const* d_in, const int* in_sizes, int n_in,
                              void* d_out, int out_size, void* d_ws, size_t ws_size,
                              hipStream_t stream) {
  const float* all_rois = (const float*)d_in[0];
  const float* gt_boxes = (const float*)d_in[1];
  const int*   gt_labels = (const int*)d_in[2];
  const int N = in_sizes[0] / 5;
  const int G = in_sizes[2];
  const int M = N + G;

  // workspace: [meta 256B][hist 32KB][score M*4][cand 64KB]
  char* ws = (char*)d_ws;
  int* meta = (int*)ws;                       // [0]=cnt_fg [1]=cnt_bg [2]=done
  uint32_t* hist = (uint32_t*)(ws + 256);
  size_t off = 256 + (size_t)2 * NBINS * 4;
  uint32_t* score = (uint32_t*)(ws + off);
  off += (((size_t)M * 4) + 255) & ~(size_t)255;
  uint64_t* cand = (uint64_t*)(ws + off);
  float* out = (float*)d_out;

  hipMemsetAsync(ws, 0, 256 + (size_t)2 * NBINS * 4, stream);
  score_kernel<<<(M + 255) / 256, 256, 0, stream>>>(all_rois, gt_boxes, score,
                                                    hist, N, M, G);
  const int cblocks = (M + CBLOCK - 1) / CBLOCK;
  compact_final_kernel<<<cblocks, CBLOCK, 0, stream>>>(all_rois, gt_boxes,
                                                       gt_labels, score, hist,
                                                       meta, cand, out, N, M);
}